// Round 6
// baseline (426.695 us; speedup 1.0000x reference)
//
#include <hip/hip_runtime.h>

#define THREADS 256
#define ETHREADS 512
#define EWPB (ETHREADS / 64)
#define WPB (THREADS / 64)
#define RPB 64            // rows per bucket staged in LDS (32KB f16)
#define CGRP 16           // col-groups per bucket (3.2MB col window)
#define MAXKEY 25008      // ceil(100000/64) * 16
#define CAPS 192          // per-key region capacity (mean 128 + 5.7 sigma; overflow spilled exactly)
#define CHUNK 6250        // edges per bin block
#define EPT 25            // EPT*256 >= CHUNK
#define OVF_CAP 8192

typedef _Float16 h2 __attribute__((ext_vector_type(2)));
union H2U { unsigned u; h2 h; _Float16 s[2]; };

#if defined(__has_builtin)
#if __has_builtin(__builtin_amdgcn_fdot2)
#define HAVE_FDOT2 1
#endif
#endif
#ifdef HAVE_FDOT2
__device__ __forceinline__ float fdot2(unsigned a, unsigned b, float c) {
    H2U ua, ub; ua.u = a; ub.u = b;
    return __builtin_amdgcn_fdot2(ua.h, ub.h, c, false);
}
#else
__device__ __forceinline__ float fdot2(unsigned a, unsigned b, float c) {
    H2U ua, ub; ua.u = a; ub.u = b;
    return fmaf((float)ua.s[1], (float)ub.s[1], fmaf((float)ua.s[0], (float)ub.s[0], c));
}
#endif

__global__ void init_acc_kernel(double* acc) { *acc = 0.0; }

// quantize fp32 -> f16 (RNE); |x|<=8 so no overflow concerns
__global__ __launch_bounds__(THREADS) void quant_kernel(
    const float* __restrict__ x, unsigned short* __restrict__ xh, int n4)
{
    int i = blockIdx.x * blockDim.x + threadIdx.x;
    const int st = gridDim.x * blockDim.x;
    for (; i < n4; i += st) {
        float4 v = ((const float4*)x)[i];
        H2U p0, p1;
        p0.s[0] = (_Float16)v.x; p0.s[1] = (_Float16)v.y;
        p1.s[0] = (_Float16)v.z; p1.s[1] = (_Float16)v.w;
        uint2 o; o.x = p0.u; o.y = p1.u;
        ((uint2*)xh)[i] = o;
    }
}

__device__ __forceinline__ int edge_key(int r, int c, int cdiv) {
    int cg = c / cdiv;
    if (cg > CGRP - 1) cg = CGRP - 1;
    return (r >> 6) * CGRP + cg;
}

// One-pass binning into fixed-capacity per-key regions; block-owned runs keep
// each output line on one XCD. Overflow (P~1e-4) spills to an exact list.
__global__ __launch_bounds__(THREADS) void bin_kernel(
    const int* __restrict__ rows, const int* __restrict__ cols,
    const float* __restrict__ vals, unsigned* __restrict__ cur,
    uint2* __restrict__ rec, unsigned* __restrict__ ovf_cnt,
    uint4* __restrict__ ovf, int nnz, int nkey, int cdiv)
{
    __shared__ unsigned hcnt[MAXKEY];    // 100 KB (reused: count -> global start)
    const int tid = threadIdx.x;
    for (int k = tid; k < nkey; k += THREADS) hcnt[k] = 0u;
    __syncthreads();

    const int cbase = blockIdx.x * CHUNK;
    const int cend  = min(cbase + CHUNK, nnz);
    unsigned short rnk[EPT];

    #pragma unroll
    for (int i = 0; i < EPT; ++i) {
        int e = cbase + tid + i * THREADS;
        rnk[i] = 0;
        if (e < cend) {
            int key = edge_key(rows[e], cols[e], cdiv);
            rnk[i] = (unsigned short)atomicAdd(&hcnt[key], 1u);
        }
    }
    __syncthreads();

    for (int k = tid; k < nkey; k += THREADS) {
        unsigned c = hcnt[k];
        unsigned gs = 0;
        if (c) gs = atomicAdd(&cur[k], c);
        hcnt[k] = gs;                     // reuse hist as block's global start
    }
    __syncthreads();

    #pragma unroll
    for (int i = 0; i < EPT; ++i) {
        int e = cbase + tid + i * THREADS;
        if (e < cend) {
            int r = rows[e], c = cols[e];
            int key = edge_key(r, c, cdiv);
            unsigned pos = hcnt[key] + (unsigned)rnk[i];
            if (pos < CAPS) {
                uint2 m;
                m.x = (unsigned)c | ((unsigned)(r & (RPB - 1)) << 17);
                m.y = __float_as_uint(vals[e]);
                rec[(size_t)key * CAPS + pos] = m;
            } else {                      // exact overflow spill
                unsigned oi = atomicAdd(ovf_cnt, 1u);
                if (oi < OVF_CAP) {
                    uint4 m4; m4.x = (unsigned)r; m4.y = (unsigned)c;
                    m4.z = __float_as_uint(vals[e]); m4.w = 0u;
                    ovf[oi] = m4;
                }
            }
        }
    }
}

// block = bucket: 64 rows (32KB f16) in LDS; 8 waves share flat batches over
// the 16 col-group regions (prefix-sum mapping keeps cg-ascending sweep).
__global__ __launch_bounds__(ETHREADS, 8) void edge_lds_kernel(
    const unsigned short* __restrict__ xh, const uint2* __restrict__ rec,
    const unsigned* __restrict__ cur, double* __restrict__ acc, int nodes)
{
    __shared__ unsigned short lrow[RPB * 256];   // 32 KB
    __shared__ unsigned s_pre[CGRP + 1];
    __shared__ float wsum[EWPB];
    const int b     = blockIdx.x;
    const int rbase = b * RPB;
    const int nrow  = min(RPB, nodes - rbase);
    const int tid   = threadIdx.x;

    if (tid < CGRP) {
        unsigned c = cur[b * CGRP + tid];
        s_pre[tid + 1] = (c > CAPS) ? (unsigned)CAPS : c;   // counts first
    }
    // stage bucket rows: coalesced int4 copy
    const int4* src = (const int4*)(xh + (size_t)rbase * 256);
    int4* dst = (int4*)lrow;
    const int nv = nrow * 32;
    for (int t = tid; t < nv; t += ETHREADS) dst[t] = src[t];
    __syncthreads();
    if (tid == 0) {
        unsigned a = 0;
        s_pre[0] = 0;
        #pragma unroll
        for (int k = 1; k <= CGRP; ++k) { a += s_pre[k]; s_pre[k] = a; }
    }
    __syncthreads();

    const int lane = tid & 63;
    const int wid  = tid >> 6;
    const unsigned T = s_pre[CGRP];
    const unsigned nbatch = (T + 63) >> 6;
    const unsigned base_rec = (unsigned)b * CGRP * CAPS;

    float lacc0 = 0.0f, lacc1 = 0.0f;

    for (unsigned t = wid; t < nbatch; t += EWPB) {
        unsigned f = (t << 6) + (unsigned)lane;
        unsigned lo = 0; float v = 0.0f;
        if (f < T) {
            int cg = 0;
            #pragma unroll
            for (int k = 1; k < CGRP; ++k) cg += (f >= s_pre[k]);
            unsigned idx = f - s_pre[cg];
            uint2 m = rec[base_rec + (unsigned)cg * CAPS + idx];
            lo = m.x; v = __uint_as_float(m.y);
        }
        #pragma unroll 4
        for (int j = 0; j < 64; j += 2) {
            {
                unsigned loj = __shfl(lo, j);
                float    vj  = __shfl(v, j);
                const int cj  = (int)(loj & 0x1FFFFu);
                const int rlj = (int)(loj >> 17);
                uint2 a4 = ((const uint2*)(lrow + rlj * 256))[lane];
                uint2 b4 = ((const uint2*)(xh + (size_t)cj * 256))[lane];
                float s = fdot2(a4.x, b4.x, 0.0f);
                s = fdot2(a4.y, b4.y, s);
                lacc0 = fmaf(vj, s, lacc0);
            }
            {
                unsigned loj = __shfl(lo, j + 1);
                float    vj  = __shfl(v, j + 1);
                const int cj  = (int)(loj & 0x1FFFFu);
                const int rlj = (int)(loj >> 17);
                uint2 a4 = ((const uint2*)(lrow + rlj * 256))[lane];
                uint2 b4 = ((const uint2*)(xh + (size_t)cj * 256))[lane];
                float s = fdot2(a4.x, b4.x, 0.0f);
                s = fdot2(a4.y, b4.y, s);
                lacc1 = fmaf(vj, s, lacc1);
            }
        }
    }

    float lacc = lacc0 + lacc1;
    #pragma unroll
    for (int o = 32; o > 0; o >>= 1) lacc += __shfl_down(lacc, o);
    if (lane == 0) wsum[wid] = lacc;
    __syncthreads();
    if (tid == 0) {
        float bs = 0.0f;
        #pragma unroll
        for (int w = 0; w < EWPB; ++w) bs += wsum[w];
        atomicAdd(acc, (double)bs);
    }
}

// exact processing of spilled edges (expected 0; <=OVF_CAP)
__global__ __launch_bounds__(THREADS) void ovf_kernel(
    const unsigned short* __restrict__ xh, const unsigned* __restrict__ ovf_cnt,
    const uint4* __restrict__ ovf, double* __restrict__ acc)
{
    __shared__ float wsum[WPB];
    const int lane = threadIdx.x & 63;
    const int wid  = threadIdx.x >> 6;
    const unsigned n = min(*ovf_cnt, (unsigned)OVF_CAP);
    float lacc = 0.0f;
    for (unsigned i = wid; i < n; i += WPB) {
        uint4 m = ovf[i];
        const unsigned r = m.x, c = m.y;
        const float v = __uint_as_float(m.z);
        uint2 a4 = ((const uint2*)(xh + (size_t)r * 256))[lane];
        uint2 b4 = ((const uint2*)(xh + (size_t)c * 256))[lane];
        float s = fdot2(a4.x, b4.x, 0.0f);
        s = fdot2(a4.y, b4.y, s);
        lacc = fmaf(v, s, lacc);
    }
    #pragma unroll
    for (int o = 32; o > 0; o >>= 1) lacc += __shfl_down(lacc, o);
    if (lane == 0) wsum[wid] = lacc;
    __syncthreads();
    if (threadIdx.x == 0) {
        float bs = 0.0f;
        #pragma unroll
        for (int w = 0; w < WPB; ++w) bs += wsum[w];
        if (n) atomicAdd(acc, (double)bs);
    }
}

// ---- fallback: unsorted f16 kernel (ws fits quant only) ----
__global__ __launch_bounds__(THREADS) void edge_dot_q_kernel(
    const unsigned short* __restrict__ xh,
    const int* __restrict__ rows, const int* __restrict__ cols,
    const float* __restrict__ vals, double* __restrict__ acc, int nnz)
{
    __shared__ float wsum[WPB];
    const int lane  = threadIdx.x & 63;
    const int wid   = threadIdx.x >> 6;
    const int gwave = blockIdx.x * WPB + wid;
    const int nwave = gridDim.x * WPB;
    float lacc = 0.0f;
    for (int base = gwave * 64; base < nnz; base += nwave * 64) {
        int e = base + lane;
        int r = 0, c = 0; float v = 0.0f;
        if (e < nnz) { r = rows[e]; c = cols[e]; v = vals[e]; }
        #pragma unroll 8
        for (int j = 0; j < 64; ++j) {
            int rj = __shfl(r, j); int cj = __shfl(c, j); float vj = __shfl(v, j);
            uint2 a4 = ((const uint2*)(xh + (size_t)rj * 256))[lane];
            uint2 b4 = ((const uint2*)(xh + (size_t)cj * 256))[lane];
            float s = fdot2(a4.x, b4.x, 0.0f);
            s = fdot2(a4.y, b4.y, s);
            lacc = fmaf(vj, s, lacc);
        }
    }
    #pragma unroll
    for (int o = 32; o > 0; o >>= 1) lacc += __shfl_down(lacc, o);
    if (lane == 0) wsum[wid] = lacc;
    __syncthreads();
    if (threadIdx.x == 0) {
        float bs = 0.0f;
        #pragma unroll
        for (int w = 0; w < WPB; ++w) bs += wsum[w];
        atomicAdd(acc, (double)bs);
    }
}

// ---- fallback: fp32 kernel ----
__global__ __launch_bounds__(THREADS) void edge_dot_kernel(
    const float* __restrict__ x,
    const int* __restrict__ rows, const int* __restrict__ cols,
    const float* __restrict__ vals, double* __restrict__ acc, int nnz)
{
    __shared__ float wsum[WPB];
    const int lane  = threadIdx.x & 63;
    const int wid   = threadIdx.x >> 6;
    const int gwave = blockIdx.x * WPB + wid;
    const int nwave = gridDim.x * WPB;
    float lacc = 0.0f;
    for (int base = gwave * 64; base < nnz; base += nwave * 64) {
        int e = base + lane;
        int r = 0, c = 0; float v = 0.0f;
        if (e < nnz) { r = rows[e]; c = cols[e]; v = vals[e]; }
        #pragma unroll 4
        for (int j = 0; j < 64; ++j) {
            int rj = __shfl(r, j); int cj = __shfl(c, j); float vj = __shfl(v, j);
            const float4 a = ((const float4*)(x + (size_t)rj * 256))[lane];
            const float4 b = ((const float4*)(x + (size_t)cj * 256))[lane];
            float s = a.x * b.x;
            s = fmaf(a.y, b.y, s);
            s = fmaf(a.z, b.z, s);
            s = fmaf(a.w, b.w, s);
            lacc = fmaf(vj, s, lacc);
        }
    }
    #pragma unroll
    for (int o = 32; o > 0; o >>= 1) lacc += __shfl_down(lacc, o);
    if (lane == 0) wsum[wid] = lacc;
    __syncthreads();
    if (threadIdx.x == 0) {
        float bs = 0.0f;
        #pragma unroll
        for (int w = 0; w < WPB; ++w) bs += wsum[w];
        atomicAdd(acc, (double)bs);
    }
}

__global__ void finalize_kernel(const double* __restrict__ acc,
                                float* __restrict__ out, int nnz)
{
    out[0] = (float)(*acc / (double)nnz);
}

static inline size_t align256(size_t x) { return (x + 255) & ~(size_t)255; }

extern "C" void kernel_launch(void* const* d_in, const int* in_sizes, int n_in,
                              void* d_out, int out_size, void* d_ws, size_t ws_size,
                              hipStream_t stream) {
    const float* x    = (const float*)d_in[0];
    const int*   rows = (const int*)d_in[1];
    const int*   cols = (const int*)d_in[2];
    const float* vals = (const float*)d_in[3];
    const int nnz   = in_sizes[1];
    const int nelem = in_sizes[0];
    const int nodes = nelem / 256;

    const int nbuck = (nodes + RPB - 1) / RPB;
    const int nkey  = nbuck * CGRP;
    const int cdiv  = (nodes + CGRP - 1) / CGRP;

    double* acc = (double*)d_ws;
    float*  out = (float*)d_out;

    // workspace layout (audited vs proven ws >= 90,000,648 B)
    size_t o_xh   = 256;
    size_t o_rec  = align256(o_xh  + (size_t)nelem * 2);              // 51.2 MB
    size_t o_cur  = align256(o_rec + (size_t)nkey * CAPS * 8);        // 38.4 MB
    size_t o_ovfc = align256(o_cur + (size_t)nkey * 4);
    size_t o_ovf  = align256(o_ovfc + 4);
    size_t need_bin   = o_ovf + (size_t)OVF_CAP * 16;
    size_t need_quant = o_xh + (size_t)nelem * 2;

    init_acc_kernel<<<1, 1, 0, stream>>>(acc);

    if (ws_size >= need_bin && nkey <= MAXKEY) {
        unsigned short* xh  = (unsigned short*)((char*)d_ws + o_xh);
        uint2*          rec = (uint2*)((char*)d_ws + o_rec);
        unsigned*       cur = (unsigned*)((char*)d_ws + o_cur);
        unsigned*       ovc = (unsigned*)((char*)d_ws + o_ovfc);
        uint4*          ovf = (uint4*)((char*)d_ws + o_ovf);

        hipMemsetAsync(cur, 0, (size_t)nkey * 4, stream);
        hipMemsetAsync(ovc, 0, 4, stream);
        quant_kernel<<<2048, THREADS, 0, stream>>>(x, xh, nelem / 4);
        const int nbb = (nnz + CHUNK - 1) / CHUNK;
        bin_kernel<<<nbb, THREADS, 0, stream>>>(rows, cols, vals, cur, rec, ovc, ovf, nnz, nkey, cdiv);
        edge_lds_kernel<<<nbuck, ETHREADS, 0, stream>>>(xh, rec, cur, acc, nodes);
        ovf_kernel<<<1, THREADS, 0, stream>>>(xh, ovc, ovf, acc);
    } else if (ws_size >= need_quant) {
        unsigned short* xh = (unsigned short*)((char*)d_ws + o_xh);
        quant_kernel<<<2048, THREADS, 0, stream>>>(x, xh, nelem / 4);
        edge_dot_q_kernel<<<2048, THREADS, 0, stream>>>(xh, rows, cols, vals, acc, nnz);
    } else {
        edge_dot_kernel<<<2048, THREADS, 0, stream>>>(x, rows, cols, vals, acc, nnz);
    }

    finalize_kernel<<<1, 1, 0, stream>>>(acc, out, nnz);
}

// Round 7
// 316.132 us; speedup vs baseline: 1.3497x; 1.3497x over previous
//
#include <hip/hip_runtime.h>

#define THREADS 256
#define WPB (THREADS / 64)
#define RPB 64            // rows per bucket staged in LDS (32KB f16)
#define CGRP 8            // col-groups per bucket (6.4MB col window)
#define MAXKEY 12504      // ceil(100000/64) * 8
#define CAPS 320          // per-key capacity: mean 256 + 4 sigma; overflow spilled exactly
#define CHUNK 6250        // edges per bin block
#define EPT 25            // EPT*256 >= CHUNK
#define OVF_CAP 8192

typedef _Float16 h2 __attribute__((ext_vector_type(2)));
union H2U { unsigned u; h2 h; _Float16 s[2]; };

#if defined(__has_builtin)
#if __has_builtin(__builtin_amdgcn_fdot2)
#define HAVE_FDOT2 1
#endif
#endif
#ifdef HAVE_FDOT2
__device__ __forceinline__ float fdot2(unsigned a, unsigned b, float c) {
    H2U ua, ub; ua.u = a; ub.u = b;
    return __builtin_amdgcn_fdot2(ua.h, ub.h, c, false);
}
#else
__device__ __forceinline__ float fdot2(unsigned a, unsigned b, float c) {
    H2U ua, ub; ua.u = a; ub.u = b;
    return fmaf((float)ua.s[1], (float)ub.s[1], fmaf((float)ua.s[0], (float)ub.s[0], c));
}
#endif

__global__ void init_acc_kernel(double* acc) { *acc = 0.0; }

// quantize fp32 -> f16 (RNE); |x|<=8 so no overflow concerns
__global__ __launch_bounds__(THREADS) void quant_kernel(
    const float* __restrict__ x, unsigned short* __restrict__ xh, int n4)
{
    int i = blockIdx.x * blockDim.x + threadIdx.x;
    const int st = gridDim.x * blockDim.x;
    for (; i < n4; i += st) {
        float4 v = ((const float4*)x)[i];
        H2U p0, p1;
        p0.s[0] = (_Float16)v.x; p0.s[1] = (_Float16)v.y;
        p1.s[0] = (_Float16)v.z; p1.s[1] = (_Float16)v.w;
        uint2 o; o.x = p0.u; o.y = p1.u;
        ((uint2*)xh)[i] = o;
    }
}

__device__ __forceinline__ int edge_key(int r, int c, int cdiv) {
    int cg = c / cdiv;
    if (cg > CGRP - 1) cg = CGRP - 1;
    return (r >> 6) * CGRP + cg;
}

// One-pass binning into fixed-capacity per-key regions; block-owned runs keep
// each output line on one XCD. Overflow (P ~ 1e-5) spills to an exact list.
__global__ __launch_bounds__(THREADS) void bin_kernel(
    const int* __restrict__ rows, const int* __restrict__ cols,
    const float* __restrict__ vals, unsigned* __restrict__ cur,
    uint2* __restrict__ rec, unsigned* __restrict__ ovf_cnt,
    uint4* __restrict__ ovf, int nnz, int nkey, int cdiv)
{
    __shared__ unsigned hcnt[MAXKEY];    // 50 KB (reused: count -> block global start)
    const int tid = threadIdx.x;
    for (int k = tid; k < nkey; k += THREADS) hcnt[k] = 0u;
    __syncthreads();

    const int cbase = blockIdx.x * CHUNK;
    const int cend  = min(cbase + CHUNK, nnz);
    unsigned short rnk[EPT];

    #pragma unroll
    for (int i = 0; i < EPT; ++i) {
        int e = cbase + tid + i * THREADS;
        rnk[i] = 0;
        if (e < cend) {
            int key = edge_key(rows[e], cols[e], cdiv);
            rnk[i] = (unsigned short)atomicAdd(&hcnt[key], 1u);
        }
    }
    __syncthreads();

    for (int k = tid; k < nkey; k += THREADS) {
        unsigned c = hcnt[k];
        unsigned gs = 0;
        if (c) gs = atomicAdd(&cur[k], c);
        hcnt[k] = gs;                     // reuse hist as block's global start
    }
    __syncthreads();

    #pragma unroll
    for (int i = 0; i < EPT; ++i) {
        int e = cbase + tid + i * THREADS;
        if (e < cend) {
            int r = rows[e], c = cols[e];
            int key = edge_key(r, c, cdiv);
            unsigned pos = hcnt[key] + (unsigned)rnk[i];
            if (pos < CAPS) {
                uint2 m;
                m.x = (unsigned)c | ((unsigned)(r & (RPB - 1)) << 17);
                m.y = __float_as_uint(vals[e]);
                rec[(size_t)key * CAPS + pos] = m;
            } else {                      // exact overflow spill
                unsigned oi = atomicAdd(ovf_cnt, 1u);
                if (oi < OVF_CAP) {
                    uint4 m4; m4.x = (unsigned)r; m4.y = (unsigned)c;
                    m4.z = __float_as_uint(vals[e]); m4.w = 0u;
                    ovf[oi] = m4;
                }
            }
        }
    }
}

// block = bucket: 64 rows (32KB f16) in LDS. Two edges in flight per wave:
// each 32-lane half covers one edge with uint4 (16B) loads -> one coalesced
// dwordx4 instruction fetches two 512B col rows; shfl chain halved; deep
// unroll + free VGPRs keep ~8 gathers outstanding (MLP, the r6 bottleneck).
__global__ __launch_bounds__(THREADS) void edge_lds_kernel(
    const unsigned short* __restrict__ xh, const uint2* __restrict__ rec,
    const unsigned* __restrict__ cur, double* __restrict__ acc, int nodes)
{
    __shared__ unsigned short lrow[RPB * 256];   // 32 KB
    __shared__ unsigned s_pre[CGRP + 1];
    __shared__ float wsum[WPB];
    const int b     = blockIdx.x;
    const int rbase = b * RPB;
    const int nrow  = min(RPB, nodes - rbase);
    const int tid   = threadIdx.x;

    if (tid < CGRP) {
        unsigned c = cur[b * CGRP + tid];
        s_pre[tid + 1] = (c > CAPS) ? (unsigned)CAPS : c;   // counts first
    }
    // stage bucket rows: coalesced int4 copy
    const int4* src = (const int4*)(xh + (size_t)rbase * 256);
    int4* dst = (int4*)lrow;
    const int nv = nrow * 32;
    for (int t = tid; t < nv; t += THREADS) dst[t] = src[t];
    __syncthreads();
    if (tid == 0) {
        unsigned a = 0;
        s_pre[0] = 0;
        #pragma unroll
        for (int k = 1; k <= CGRP; ++k) { a += s_pre[k]; s_pre[k] = a; }
    }
    __syncthreads();

    const int lane = tid & 63;
    const int wid  = tid >> 6;
    const int half = lane >> 5;          // which edge of the pair
    const int hl   = lane & 31;          // 16B unit within the row
    const unsigned T = s_pre[CGRP];
    const unsigned nbatch = (T + 63) >> 6;
    const unsigned base_rec = (unsigned)b * CGRP * CAPS;

    float lacc0 = 0.0f, lacc1 = 0.0f;

    for (unsigned t = wid; t < nbatch; t += WPB) {
        unsigned f = (t << 6) + (unsigned)lane;
        unsigned lo = 0; float v = 0.0f;
        if (f < T) {
            int cg = 0;
            #pragma unroll
            for (int k = 1; k < CGRP; ++k) cg += (f >= s_pre[k]);
            unsigned idx = f - s_pre[cg];
            uint2 m = rec[base_rec + (unsigned)cg * CAPS + idx];
            lo = m.x; v = __uint_as_float(m.y);
        }
        #pragma unroll 8
        for (int j = 0; j < 32; ++j) {
            const int ei = (j << 1) + half;
            unsigned loj = __shfl(lo, ei);
            float    vj  = __shfl(v, ei);
            const int cj  = (int)(loj & 0x1FFFFu);
            const int rlj = (int)(loj >> 17);
            uint4 ra = ((const uint4*)(lrow + rlj * 256))[hl];
            uint4 cb = ((const uint4*)(xh + (size_t)cj * 256))[hl];
            float s = fdot2(ra.x, cb.x, 0.0f);
            s = fdot2(ra.y, cb.y, s);
            s = fdot2(ra.z, cb.z, s);
            s = fdot2(ra.w, cb.w, s);
            if (j & 1) lacc1 = fmaf(vj, s, lacc1);
            else       lacc0 = fmaf(vj, s, lacc0);
        }
    }

    float lacc = lacc0 + lacc1;
    #pragma unroll
    for (int o = 32; o > 0; o >>= 1) lacc += __shfl_down(lacc, o);
    if (lane == 0) wsum[wid] = lacc;
    __syncthreads();
    if (tid == 0) {
        float bs = 0.0f;
        #pragma unroll
        for (int w = 0; w < WPB; ++w) bs += wsum[w];
        atomicAdd(acc, (double)bs);
    }
}

// exact processing of spilled edges (expected ~0; <=OVF_CAP)
__global__ __launch_bounds__(THREADS) void ovf_kernel(
    const unsigned short* __restrict__ xh, const unsigned* __restrict__ ovf_cnt,
    const uint4* __restrict__ ovf, double* __restrict__ acc)
{
    __shared__ float wsum[WPB];
    const int lane = threadIdx.x & 63;
    const int wid  = threadIdx.x >> 6;
    const unsigned n = min(*ovf_cnt, (unsigned)OVF_CAP);
    float lacc = 0.0f;
    for (unsigned i = wid; i < n; i += WPB) {
        uint4 m = ovf[i];
        const unsigned r = m.x, c = m.y;
        const float v = __uint_as_float(m.z);
        uint2 a4 = ((const uint2*)(xh + (size_t)r * 256))[lane];
        uint2 b4 = ((const uint2*)(xh + (size_t)c * 256))[lane];
        float s = fdot2(a4.x, b4.x, 0.0f);
        s = fdot2(a4.y, b4.y, s);
        lacc = fmaf(v, s, lacc);
    }
    #pragma unroll
    for (int o = 32; o > 0; o >>= 1) lacc += __shfl_down(lacc, o);
    if (lane == 0) wsum[wid] = lacc;
    __syncthreads();
    if (threadIdx.x == 0) {
        float bs = 0.0f;
        #pragma unroll
        for (int w = 0; w < WPB; ++w) bs += wsum[w];
        if (n) atomicAdd(acc, (double)bs);
    }
}

// ---- fallback: unsorted f16 kernel (ws fits quant only) ----
__global__ __launch_bounds__(THREADS) void edge_dot_q_kernel(
    const unsigned short* __restrict__ xh,
    const int* __restrict__ rows, const int* __restrict__ cols,
    const float* __restrict__ vals, double* __restrict__ acc, int nnz)
{
    __shared__ float wsum[WPB];
    const int lane  = threadIdx.x & 63;
    const int wid   = threadIdx.x >> 6;
    const int gwave = blockIdx.x * WPB + wid;
    const int nwave = gridDim.x * WPB;
    float lacc = 0.0f;
    for (int base = gwave * 64; base < nnz; base += nwave * 64) {
        int e = base + lane;
        int r = 0, c = 0; float v = 0.0f;
        if (e < nnz) { r = rows[e]; c = cols[e]; v = vals[e]; }
        #pragma unroll 8
        for (int j = 0; j < 64; ++j) {
            int rj = __shfl(r, j); int cj = __shfl(c, j); float vj = __shfl(v, j);
            uint2 a4 = ((const uint2*)(xh + (size_t)rj * 256))[lane];
            uint2 b4 = ((const uint2*)(xh + (size_t)cj * 256))[lane];
            float s = fdot2(a4.x, b4.x, 0.0f);
            s = fdot2(a4.y, b4.y, s);
            lacc = fmaf(vj, s, lacc);
        }
    }
    #pragma unroll
    for (int o = 32; o > 0; o >>= 1) lacc += __shfl_down(lacc, o);
    if (lane == 0) wsum[wid] = lacc;
    __syncthreads();
    if (threadIdx.x == 0) {
        float bs = 0.0f;
        #pragma unroll
        for (int w = 0; w < WPB; ++w) bs += wsum[w];
        atomicAdd(acc, (double)bs);
    }
}

// ---- fallback: fp32 kernel ----
__global__ __launch_bounds__(THREADS) void edge_dot_kernel(
    const float* __restrict__ x,
    const int* __restrict__ rows, const int* __restrict__ cols,
    const float* __restrict__ vals, double* __restrict__ acc, int nnz)
{
    __shared__ float wsum[WPB];
    const int lane  = threadIdx.x & 63;
    const int wid   = threadIdx.x >> 6;
    const int gwave = blockIdx.x * WPB + wid;
    const int nwave = gridDim.x * WPB;
    float lacc = 0.0f;
    for (int base = gwave * 64; base < nnz; base += nwave * 64) {
        int e = base + lane;
        int r = 0, c = 0; float v = 0.0f;
        if (e < nnz) { r = rows[e]; c = cols[e]; v = vals[e]; }
        #pragma unroll 4
        for (int j = 0; j < 64; ++j) {
            int rj = __shfl(r, j); int cj = __shfl(c, j); float vj = __shfl(v, j);
            const float4 a = ((const float4*)(x + (size_t)rj * 256))[lane];
            const float4 b = ((const float4*)(x + (size_t)cj * 256))[lane];
            float s = a.x * b.x;
            s = fmaf(a.y, b.y, s);
            s = fmaf(a.z, b.z, s);
            s = fmaf(a.w, b.w, s);
            lacc = fmaf(vj, s, lacc);
        }
    }
    #pragma unroll
    for (int o = 32; o > 0; o >>= 1) lacc += __shfl_down(lacc, o);
    if (lane == 0) wsum[wid] = lacc;
    __syncthreads();
    if (threadIdx.x == 0) {
        float bs = 0.0f;
        #pragma unroll
        for (int w = 0; w < WPB; ++w) bs += wsum[w];
        atomicAdd(acc, (double)bs);
    }
}

__global__ void finalize_kernel(const double* __restrict__ acc,
                                float* __restrict__ out, int nnz)
{
    out[0] = (float)(*acc / (double)nnz);
}

static inline size_t align256(size_t x) { return (x + 255) & ~(size_t)255; }

extern "C" void kernel_launch(void* const* d_in, const int* in_sizes, int n_in,
                              void* d_out, int out_size, void* d_ws, size_t ws_size,
                              hipStream_t stream) {
    const float* x    = (const float*)d_in[0];
    const int*   rows = (const int*)d_in[1];
    const int*   cols = (const int*)d_in[2];
    const float* vals = (const float*)d_in[3];
    const int nnz   = in_sizes[1];
    const int nelem = in_sizes[0];
    const int nodes = nelem / 256;

    const int nbuck = (nodes + RPB - 1) / RPB;
    const int nkey  = nbuck * CGRP;
    const int cdiv  = (nodes + CGRP - 1) / CGRP;

    double* acc = (double*)d_ws;
    float*  out = (float*)d_out;

    // workspace layout: xh 51.2MB + rec 32.0MB + cur 50KB + ovf ~128KB = 83.4MB
    size_t o_xh   = 256;
    size_t o_rec  = align256(o_xh  + (size_t)nelem * 2);
    size_t o_cur  = align256(o_rec + (size_t)nkey * CAPS * 8);
    size_t o_ovfc = align256(o_cur + (size_t)nkey * 4);
    size_t o_ovf  = align256(o_ovfc + 4);
    size_t need_bin   = o_ovf + (size_t)OVF_CAP * 16;
    size_t need_quant = o_xh + (size_t)nelem * 2;

    init_acc_kernel<<<1, 1, 0, stream>>>(acc);

    if (ws_size >= need_bin && nkey <= MAXKEY) {
        unsigned short* xh  = (unsigned short*)((char*)d_ws + o_xh);
        uint2*          rec = (uint2*)((char*)d_ws + o_rec);
        unsigned*       cur = (unsigned*)((char*)d_ws + o_cur);
        unsigned*       ovc = (unsigned*)((char*)d_ws + o_ovfc);
        uint4*          ovf = (uint4*)((char*)d_ws + o_ovf);

        hipMemsetAsync(cur, 0, (size_t)nkey * 4, stream);
        hipMemsetAsync(ovc, 0, 4, stream);
        quant_kernel<<<2048, THREADS, 0, stream>>>(x, xh, nelem / 4);
        const int nbb = (nnz + CHUNK - 1) / CHUNK;
        bin_kernel<<<nbb, THREADS, 0, stream>>>(rows, cols, vals, cur, rec, ovc, ovf, nnz, nkey, cdiv);
        edge_lds_kernel<<<nbuck, THREADS, 0, stream>>>(xh, rec, cur, acc, nodes);
        ovf_kernel<<<1, THREADS, 0, stream>>>(xh, ovc, ovf, acc);
    } else if (ws_size >= need_quant) {
        unsigned short* xh = (unsigned short*)((char*)d_ws + o_xh);
        quant_kernel<<<2048, THREADS, 0, stream>>>(x, xh, nelem / 4);
        edge_dot_q_kernel<<<2048, THREADS, 0, stream>>>(xh, rows, cols, vals, acc, nnz);
    } else {
        edge_dot_kernel<<<2048, THREADS, 0, stream>>>(x, rows, cols, vals, acc, nnz);
    }

    finalize_kernel<<<1, 1, 0, stream>>>(acc, out, nnz);
}